// Round 7
// baseline (249.170 us; speedup 1.0000x reference)
//
#include <hip/hip_runtime.h>
#include <cstdint>
#include <cstddef>

#define B_ 8
#define N_ 4096
#define C_ 512
#define KV_ 960
#define DQ 128
#define DK 240
#define NSPLIT 8   // k1 split-K: grid 32*8 = 256 blocks = 1/CU

typedef __attribute__((ext_vector_type(8))) short bf16x8;
typedef __attribute__((ext_vector_type(4))) float f32x4;
typedef __attribute__((ext_vector_type(2))) unsigned int u32x2;
#define AS1 __attribute__((address_space(1)))
#define AS3 __attribute__((address_space(3)))

__device__ __forceinline__ ushort f2bf(float f) {
  uint32_t u = __float_as_uint(f);
  u += 0x7FFFu + ((u >> 16) & 1u);  // RNE
  return (ushort)(u >> 16);
}

union frag_u {
  u32x2 p[2];
  bf16x8 v;
};

// ds_read_b64_tr_b16 with literal offset (stringified integer literal)
#define S_(x) #x
#define SX(x) S_(x)
#define TR8(dst, base, imm) \
  asm volatile("ds_read_b64_tr_b16 %0, %1 offset:" SX(imm) : "=v"(dst) : "v"(base))
#define LDFRAG(dst, base, i1, i2) \
  { frag_u f_; TR8(f_.p[0], base, i1); TR8(f_.p[1], base, i2); dst = f_.v; }

// ---------------------------------------------------------------------------
// f32 -> bf16 (RNE), 4 elems/thread
// ---------------------------------------------------------------------------
__global__ __launch_bounds__(256) void k_cvt(const float4* __restrict__ in,
                                             ushort4* __restrict__ out, int n4) {
  int i = blockIdx.x * 256 + threadIdx.x;
  if (i >= n4) return;
  float4 v = in[i];
  ushort4 o;
  o.x = f2bf(v.x); o.y = f2bf(v.y); o.z = f2bf(v.z); o.w = f2bf(v.w);
  out[i] = o;
}

// ---------------------------------------------------------------------------
// K1 v3 (MFMA, tr_b16): partial
//   S[b,h,i,j] = sum_{n in split} emb1BF[b,n,h*128+i] * embaBF[b,n,h*240+j]
// Per block (bh, split): 128i x 256j (240 valid), K = 512 n, BK = 64.
// LDS: [4n x 16col] subtiles in tr-read order, staged linearly by
// global_load_lds with per-lane pre-permuted GLOBAL source. Fragments via
// ds_read_b64_tr_b16 (per-lane addr = base + l*8; groups read consecutive
// 128B subtiles). Double-buffered 2-phase pipeline, counted waits.
// grid (32 bh, NSPLIT), block 512 (8 waves as 2i x 4j; wave tile 64x64).
// ---------------------------------------------------------------------------
__global__ __launch_bounds__(512) void k1_mfma(const ushort* __restrict__ emb1BF,
                                               const ushort* __restrict__ embaBF,
                                               float* __restrict__ P) {
  // per buf: A 16KB (8192 us) + B 32KB (16384 us) = 24576 us; 2 bufs = 96KB
  __shared__ ushort LDS_[2][24576];
  const int bh = blockIdx.x;
  const int split = blockIdx.y;
  const int b = bh >> 2, h = bh & 3;
  const int t = threadIdx.x;
  const int w = t >> 6, l = t & 63;
  const int wr = w >> 2, wn = w & 3;  // wave tile rows wr*64, cols wn*64
  const int n0 = split * (N_ / NSPLIT);

  // ---- per-lane global sources in subtile order ----
  // A subtile s = ((k*8+fm)*2+par)*4+g ; inner: row j (0..3) x col i (0..15)
  const ushort* srcA[2];
#pragma unroll
  for (int q = 0; q < 2; ++q) {
    uint byte = w * 2048 + q * 1024 + (l << 4);
    uint s = byte >> 7, inner = byte & 127;
    uint jr = inner >> 5, i0 = (inner & 31) >> 1;
    uint g = s & 3, par = (s >> 2) & 1, fmv = (s >> 3) & 7, kv = s >> 6;
    uint noff = kv * 32 + g * 8 + par * 4 + jr;
    srcA[q] = emb1BF + (size_t)b * (N_ * C_) + (size_t)(n0 + noff) * C_ +
              h * DQ + fmv * 16 + i0;
  }
  // B subtile s = ((k*16+jb)*2+par)*4+g
  const ushort* srcB[4];
#pragma unroll
  for (int q = 0; q < 4; ++q) {
    uint byte = w * 4096 + q * 1024 + (l << 4);
    uint s = byte >> 7, inner = byte & 127;
    uint jr = inner >> 5, i0 = (inner & 31) >> 1;
    uint g = s & 3, par = (s >> 2) & 1, jbv = (s >> 3) & 15, kv = s >> 7;
    uint noff = kv * 32 + g * 8 + par * 4 + jr;
    srcB[q] = embaBF + (size_t)b * (N_ * KV_) + (size_t)(n0 + noff) * KV_ +
              h * DK + jbv * 16 + i0;
  }

#define STAGE(tile, bf)                                                        \
  do {                                                                         \
    const size_t nadv = (size_t)(tile) * 64;                                   \
    _Pragma("unroll") for (int q = 0; q < 2; ++q)                              \
        __builtin_amdgcn_global_load_lds(                                      \
            (AS1 const uint32_t*)(uintptr_t)(srcA[q] + nadv * C_),             \
            (AS3 uint32_t*)(uintptr_t)&LDS_[bf][w * 1024 + q * 512], 16, 0, 0);\
    _Pragma("unroll") for (int q = 0; q < 4; ++q)                              \
        __builtin_amdgcn_global_load_lds(                                      \
            (AS1 const uint32_t*)(uintptr_t)(srcB[q] + nadv * KV_),            \
            (AS3 uint32_t*)(uintptr_t)&LDS_[bf][8192 + w * 2048 + q * 512],    \
            16, 0, 0);                                                         \
  } while (0)

  f32x4 acc[4][4];
#pragma unroll
  for (int fm = 0; fm < 4; ++fm)
#pragma unroll
    for (int fn = 0; fn < 4; ++fn) acc[fm][fn] = (f32x4){0.f, 0.f, 0.f, 0.f};

  const uint ldsbase = (uint)(size_t)&LDS_[0][0];
  const uint laneoff = (uint)(l << 3);

#define MMALL()                                                                \
  asm volatile("s_waitcnt lgkmcnt(0)" ::: "memory");                           \
  __builtin_amdgcn_sched_barrier(0);                                           \
  _Pragma("unroll") for (int fm = 0; fm < 4; ++fm)                             \
      _Pragma("unroll") for (int fn = 0; fn < 4; ++fn)                         \
      acc[fm][fn] = __builtin_amdgcn_mfma_f32_16x16x32_bf16(                   \
          af[fm], bv[fn], acc[fm][fn], 0, 0, 0)

  // prologue
  STAGE(0, 0);
  asm volatile("s_waitcnt vmcnt(0)" ::: "memory");
  __builtin_amdgcn_s_barrier();

  for (int ks = 0; ks < 8; ++ks) {
    const int buf = ks & 1;
    if (ks + 1 < 8) STAGE(ks + 1, buf ^ 1);
    const uint aA = ldsbase + (uint)buf * 49152 + (uint)wr * 4096 + laneoff;
    const uint aB = ldsbase + (uint)buf * 49152 + 16384 + (uint)wn * 4096 + laneoff;
    {  // phase k=0
      bf16x8 af[4], bv[4];
      LDFRAG(af[0], aA, 0, 512);
      LDFRAG(af[1], aA, 1024, 1536);
      LDFRAG(af[2], aA, 2048, 2560);
      LDFRAG(af[3], aA, 3072, 3584);
      LDFRAG(bv[0], aB, 0, 512);
      LDFRAG(bv[1], aB, 1024, 1536);
      LDFRAG(bv[2], aB, 2048, 2560);
      LDFRAG(bv[3], aB, 3072, 3584);
      MMALL();
    }
    {  // phase k=1
      bf16x8 af[4], bv[4];
      LDFRAG(af[0], aA, 8192, 8704);
      LDFRAG(af[1], aA, 9216, 9728);
      LDFRAG(af[2], aA, 10240, 10752);
      LDFRAG(af[3], aA, 11264, 11776);
      LDFRAG(bv[0], aB, 16384, 16896);
      LDFRAG(bv[1], aB, 17408, 17920);
      LDFRAG(bv[2], aB, 18432, 18944);
      LDFRAG(bv[3], aB, 19456, 19968);
      MMALL();
    }
    asm volatile("s_waitcnt vmcnt(0)" ::: "memory");
    __builtin_amdgcn_s_barrier();
  }
#undef STAGE
#undef MMALL

  // fragment-native coalesced store: P[split][bh][v=fm*4+fn][t] (f32x4)
  f32x4* Pv4 = (f32x4*)P + (size_t)(split * 32 + bh) * 8192;
#pragma unroll
  for (int fm = 0; fm < 4; ++fm)
#pragma unroll
    for (int fn = 0; fn < 4; ++fn) Pv4[(fm * 4 + fn) * 512 + t] = acc[fm][fn];
}

// ---------------------------------------------------------------------------
// Reduce NSPLIT fragment-native partials, un-swizzle into S[bh][128][240].
// grid (32 bh, 32), block 256.
// ---------------------------------------------------------------------------
__global__ __launch_bounds__(256) void k_reduce_frag(const f32x4* __restrict__ P,
                                                     float* __restrict__ S) {
  const int bh = blockIdx.x;
  const int g = blockIdx.y * 256 + threadIdx.x;  // 0..8191
  f32x4 a = P[(size_t)bh * 8192 + g];
#pragma unroll
  for (int s = 1; s < NSPLIT; ++s) {
    f32x4 v = P[(size_t)s * 262144 + (size_t)bh * 8192 + g];
    a.x += v.x; a.y += v.y; a.z += v.z; a.w += v.w;
  }
  const int v = g >> 9, tt = g & 511;
  const int fm = v >> 2, fn = v & 3;
  const int wv = tt >> 6, l = tt & 63;
  const int wr = wv >> 2, wc = wv & 3;
  const int i0 = wr * 64 + fm * 16 + (l >> 4) * 4;
  const int j = wc * 64 + fn * 16 + (l & 15);
  if (j < DK) {
    float* sp = S + (size_t)bh * (DQ * DK) + (size_t)i0 * DK + j;
    sp[0] = a.x; sp[DK] = a.y; sp[2 * DK] = a.z; sp[3 * DK] = a.w;
  }
}

// ===========================================================================
// Flat-batched f32 chain GEMMs (unchanged from R6).
// ===========================================================================
__global__ __launch_bounds__(256) void k_g1(const float* __restrict__ Wq,
                                            const float* __restrict__ S,
                                            float* __restrict__ U) {
  const int h = blockIdx.x, c0 = blockIdx.y * 64;
  const int b = blockIdx.z / 5, n0 = (blockIdx.z % 5) * 48;
  const float* A = Wq + (size_t)h * 16384;
  const float* Bp = S + (size_t)(b * 4 + h) * 30720 + n0;
  float* Cp = U + (size_t)(b * 4 + h) * 30720 + n0;
  __shared__ float Ast[16][65];
  __shared__ float Bst[16][49];
  const int t = threadIdx.x;
  const int mi = (t >> 4) * 4, nj = (t & 15) * 3;
  float acc[4][3] = {};
  for (int k0 = 0; k0 < 128; k0 += 16) {
    __syncthreads();
#pragma unroll
    for (int q = 0; q < 4; ++q) {
      int idx = t + q * 256, m = idx >> 4, k = idx & 15;
      Ast[k][m] = A[(size_t)(c0 + m) * 128 + k0 + k];
    }
#pragma unroll
    for (int q = 0; q < 3; ++q) {
      int idx = t + q * 256, k = idx / 48, n = idx % 48;
      Bst[k][n] = Bp[(size_t)(k0 + k) * 240 + n];
    }
    __syncthreads();
#pragma unroll
    for (int kk = 0; kk < 16; ++kk) {
      float a4[4], b3[3];
#pragma unroll
      for (int x = 0; x < 4; ++x) a4[x] = Ast[kk][mi + x];
#pragma unroll
      for (int y = 0; y < 3; ++y) b3[y] = Bst[kk][nj + y];
#pragma unroll
      for (int x = 0; x < 4; ++x)
#pragma unroll
        for (int y = 0; y < 3; ++y) acc[x][y] = fmaf(a4[x], b3[y], acc[x][y]);
    }
  }
#pragma unroll
  for (int x = 0; x < 4; ++x)
#pragma unroll
    for (int y = 0; y < 3; ++y)
      Cp[(size_t)(c0 + mi + x) * 240 + nj + y] = acc[x][y];
}

__global__ __launch_bounds__(256) void k_g2(const float* __restrict__ U,
                                            const float* __restrict__ Wk,
                                            float* __restrict__ SC) {
  const int m0 = blockIdx.x * 64, n0 = blockIdx.y * 48;
  __shared__ float Ast[16][65];
  __shared__ float Bst2[48][17];
  const int t = threadIdx.x;
  const int mi = (t >> 4) * 4, nj = (t & 15) * 3;
  float acc[4][3] = {};
  for (int k0 = 0; k0 < 240; k0 += 16) {
    __syncthreads();
#pragma unroll
    for (int q = 0; q < 4; ++q) {
      int idx = t + q * 256, m = idx >> 4, k = idx & 15;
      Ast[k][m] = U[(size_t)(m0 + m) * 240 + k0 + k];
    }
#pragma unroll
    for (int q = 0; q < 3; ++q) {
      int idx = t + q * 256, n = idx >> 4, kd = idx & 15;
      Bst2[n][kd] = Wk[(size_t)(n0 + n) * 240 + k0 + kd];
    }
    __syncthreads();
#pragma unroll
    for (int kk = 0; kk < 16; ++kk) {
      float a4[4], b3[3];
#pragma unroll
      for (int x = 0; x < 4; ++x) a4[x] = Ast[kk][mi + x];
#pragma unroll
      for (int y = 0; y < 3; ++y) b3[y] = Bst2[nj + y][kk];
#pragma unroll
      for (int x = 0; x < 4; ++x)
#pragma unroll
        for (int y = 0; y < 3; ++y) acc[x][y] = fmaf(a4[x], b3[y], acc[x][y]);
    }
  }
  const float scale = 0.0322748612183951f;
#pragma unroll
  for (int x = 0; x < 4; ++x)
#pragma unroll
    for (int y = 0; y < 3; ++y)
      SC[(size_t)(m0 + mi + x) * 240 + n0 + nj + y] = acc[x][y] * scale;
}

__global__ __launch_bounds__(256) void k_g3(const float* __restrict__ PR,
                                            const float* __restrict__ Wv,
                                            float* __restrict__ T) {
  const int m0 = blockIdx.x * 64, n0 = blockIdx.y * 48;
  __shared__ float Ast[16][65];
  __shared__ float Bst[16][49];
  const int t = threadIdx.x;
  const int mi = (t >> 4) * 4, nj = (t & 15) * 3;
  float acc[4][3] = {};
  for (int k0 = 0; k0 < 240; k0 += 16) {
    __syncthreads();
#pragma unroll
    for (int q = 0; q < 4; ++q) {
      int idx = t + q * 256, m = idx >> 4, k = idx & 15;
      Ast[k][m] = PR[(size_t)(m0 + m) * 240 + k0 + k];
    }
#pragma unroll
    for (int q = 0; q < 3; ++q) {
      int idx = t + q * 256, k = idx / 48, n = idx % 48;
      Bst[k][n] = Wv[(size_t)(k0 + k) * 240 + n0 + n];
    }
    __syncthreads();
#pragma unroll
    for (int kk = 0; kk < 16; ++kk) {
      float a4[4], b3[3];
#pragma unroll
      for (int x = 0; x < 4; ++x) a4[x] = Ast[kk][mi + x];
#pragma unroll
      for (int y = 0; y < 3; ++y) b3[y] = Bst[kk][nj + y];
#pragma unroll
      for (int x = 0; x < 4; ++x)
#pragma unroll
        for (int y = 0; y < 3; ++y) acc[x][y] = fmaf(a4[x], b3[y], acc[x][y]);
    }
  }
#pragma unroll
  for (int x = 0; x < 4; ++x)
#pragma unroll
    for (int y = 0; y < 3; ++y)
      T[(size_t)(m0 + mi + x) * 240 + n0 + nj + y] = acc[x][y];
}

__global__ __launch_bounds__(256) void k_g4(const float* __restrict__ Wo,
                                            const float* __restrict__ T,
                                            ushort* __restrict__ W3bf) {
  const int h = blockIdx.x, e0 = blockIdx.y * 64;
  const int b = blockIdx.z / 5, n0 = (blockIdx.z % 5) * 48;
  const float* Bp = T + (size_t)(b * 4 + h) * 30720 + n0;
  ushort* Cp = W3bf + (size_t)b * 491520 + h * 240 + n0;
  __shared__ float Ast[16][65];
  __shared__ float Bst[16][49];
  const int t = threadIdx.x;
  const int mi = (t >> 4) * 4, nj = (t & 15) * 3;
  float acc[4][3] = {};
  for (int k0 = 0; k0 < 128; k0 += 16) {
    __syncthreads();
#pragma unroll
    for (int q = 0; q < 4; ++q) {
      int idx = t + q * 256, m = idx >> 4, k = idx & 15;
      Ast[k][m] = Wo[(size_t)(e0 + m) * 512 + 4 * (k0 + k) + h];
    }
#pragma unroll
    for (int q = 0; q < 3; ++q) {
      int idx = t + q * 256, k = idx / 48, n = idx % 48;
      Bst[k][n] = Bp[(size_t)(k0 + k) * 240 + n];
    }
    __syncthreads();
#pragma unroll
    for (int kk = 0; kk < 16; ++kk) {
      float a4[4], b3[3];
#pragma unroll
      for (int x = 0; x < 4; ++x) a4[x] = Ast[kk][mi + x];
#pragma unroll
      for (int y = 0; y < 3; ++y) b3[y] = Bst[kk][nj + y];
#pragma unroll
      for (int x = 0; x < 4; ++x)
#pragma unroll
        for (int y = 0; y < 3; ++y) acc[x][y] = fmaf(a4[x], b3[y], acc[x][y]);
    }
  }
#pragma unroll
  for (int x = 0; x < 4; ++x)
#pragma unroll
    for (int y = 0; y < 3; ++y)
      Cp[(size_t)(e0 + mi + x) * 960 + nj + y] = f2bf(acc[x][y]);
}

// ---------------------------------------------------------------------------
// Stats + softmax (unchanged from R6).
// ---------------------------------------------------------------------------
__global__ __launch_bounds__(1024) void k_stats(const float* __restrict__ SC,
                                                float* __restrict__ stats) {
  const int bh = blockIdx.x;
  const float* s = SC + (size_t)bh * 30720;
  const int t = threadIdx.x;
  float sum = 0.f, sq = 0.f;
  for (int i = t; i < 30720; i += 1024) {
    float v = s[i];
    sum += v;
    sq = fmaf(v, v, sq);
  }
#pragma unroll
  for (int o = 32; o > 0; o >>= 1) {
    sum += __shfl_down(sum, o);
    sq += __shfl_down(sq, o);
  }
  __shared__ float s1[16], s2[16];
  if ((t & 63) == 0) { s1[t >> 6] = sum; s2[t >> 6] = sq; }
  __syncthreads();
  if (t == 0) {
    float ts = 0.f, tq = 0.f;
#pragma unroll
    for (int i = 0; i < 16; ++i) { ts += s1[i]; tq += s2[i]; }
    const float mu = ts * (1.f / 30720.f);
    const float var = tq * (1.f / 30720.f) - mu * mu;
    stats[bh * 2] = mu;
    stats[bh * 2 + 1] = rsqrtf(var + 1e-5f);
  }
}

__global__ __launch_bounds__(512) void k_softmax(const float* __restrict__ SC,
                                                 const float* __restrict__ stats,
                                                 float* __restrict__ PR) {
  const int bh = blockIdx.x;
  const float mu = stats[bh * 2], rstd = stats[bh * 2 + 1];
  const int wv = threadIdx.x >> 6, l = threadIdx.x & 63;
  const int row0 = blockIdx.y * 32 + wv * 4;
  const float* s = SC + (size_t)bh * 30720;
  float* p = PR + (size_t)bh * 30720;
#pragma unroll
  for (int r = 0; r < 4; ++r) {
    const float* srow = s + (size_t)(row0 + r) * 240;
    float* prow = p + (size_t)(row0 + r) * 240;
    float x0 = (srow[l] - mu) * rstd;
    float x1 = (srow[64 + l] - mu) * rstd;
    float x2 = (srow[128 + l] - mu) * rstd;
    float x3 = (l < 48) ? (srow[192 + l] - mu) * rstd : -1e30f;
    float m = fmaxf(fmaxf(x0, x1), fmaxf(x2, x3));
#pragma unroll
    for (int o = 32; o > 0; o >>= 1) m = fmaxf(m, __shfl_xor(m, o));
    float e0 = __expf(x0 - m), e1 = __expf(x1 - m), e2 = __expf(x2 - m);
    float e3 = (l < 48) ? __expf(x3 - m) : 0.f;
    float ss = e0 + e1 + e2 + e3;
#pragma unroll
    for (int o = 32; o > 0; o >>= 1) ss += __shfl_xor(ss, o);
    const float inv = 1.f / ss;
    prow[l] = e0 * inv;
    prow[64 + l] = e1 * inv;
    prow[128 + l] = e2 * inv;
    if (l < 48) prow[192 + l] = e3 * inv;
  }
}

// ---------------------------------------------------------------------------
// K3 (MFMA): unchanged (128x128 tile, XCD-swizzled flat grid).
// ---------------------------------------------------------------------------
__global__ __launch_bounds__(256) void k3_mfma(const ushort* __restrict__ A,
                                               const ushort* __restrict__ Bw,
                                               float* __restrict__ C) {
  __shared__ ushort As[128 * 32];
  __shared__ ushort Bs[128 * 32];
  const int bid = blockIdx.x;
  const int swz = (bid & 7) * 128 + (bid >> 3);
  const int b = swz >> 7;
  const int rem = swz & 127;
  const int mt = rem >> 2, nt = rem & 3;
  const int t = threadIdx.x;
  const int w = t >> 6, l = t & 63;
  const int wr = w >> 1, wc = w & 1;

  const ushort* Ab = A + (size_t)b * N_ * KV_ + (size_t)mt * 128 * KV_;
  const ushort* Bb = Bw + (size_t)b * C_ * KV_ + (size_t)nt * 128 * KV_;

  const int r_l = l >> 2;
  const int c_l = (l & 3) * 8;

  f32x4 acc[4][4];
#pragma unroll
  for (int fm = 0; fm < 4; ++fm)
#pragma unroll
    for (int fn = 0; fn < 4; ++fn) acc[fm][fn] = (f32x4){0.f, 0.f, 0.f, 0.f};

  const int lrow = l & 15;
  const int lk = (l >> 4) * 8;

  for (int k0 = 0; k0 < KV_; k0 += 32) {
#pragma unroll
    for (int inst = 0; inst < 2; ++inst) {
      const int gi = w * 2 + inst;
      const ushort* ga = Ab + (size_t)(gi * 16 + r_l) * KV_ + k0 + c_l;
      __builtin_amdgcn_global_load_lds((AS1 const uint32_t*)(uintptr_t)ga,
                                       (AS3 uint32_t*)(uintptr_t)(As + gi * 512),
                                       16, 0, 0);
      const ushort* gb = Bb + (size_t)(gi * 16 + r_l) * KV_ + k0 + c_l;
      __builtin_amdgcn_global_load_lds((AS1 const uint32_t*)(uintptr_t)gb,
                                       (AS3 uint32_t*)(uintptr_t)(Bs + gi * 512),
                                       16, 0, 0);
    }
    __syncthreads();
    bf16x8 af[4], bfr[4];
#pragma unroll
    for (int fm = 0; fm < 4; ++fm)
      af[fm] = *(const bf16x8*)(As + (wr * 64 + fm * 16 + lrow) * 32 + lk);
#pragma unroll
    for (int fn = 0; fn < 4; ++fn)
      bfr[fn] = *(const bf16x8*)(Bs + (wc * 64 + fn * 16 + lrow) * 32 + lk);
#pragma unroll
    for (int fm = 0; fm < 4; ++fm)
#pragma unroll
      for (int fn = 0; fn < 4; ++fn)
        acc[fm][fn] = __builtin_amdgcn_mfma_f32_16x16x32_bf16(af[fm], bfr[fn],
                                                              acc[fm][fn], 0, 0, 0);
    __syncthreads();
  }

  float* Cb = C + (size_t)b * N_ * C_ + ((size_t)mt * 128) * C_ + nt * 128;
  const int col = wc * 64 + (l & 15);
  const int rbase = wr * 64 + (l >> 4) * 4;
#pragma unroll
  for (int fm = 0; fm < 4; ++fm)
#pragma unroll
    for (int fn = 0; fn < 4; ++fn)
#pragma unroll
      for (int r = 0; r < 4; ++r)
        Cb[(size_t)(rbase + fm * 16 + r) * C_ + col + fn * 16] = acc[fm][fn][r];
}

// ---------------------------------------------------------------------------
// Memory plan (ws 78,643,200 B + d_out 67,108,864 B as scratch):
//   d_out [0, 33554432)          P frag-partials  -- dead before k3
//   d_out [33554432, 67108864)   emb1BF (bf16)    -- dead before k3
//   ws [0, 62914560)             embaBF (bf16)
//   ws [62914560, 66846720)      S (f32) -> then T (f32, after g1)
//   ws [66846720, 70778880)      U (f32); stats overlays after g2; W3bf later
//   ws [70778880, 74711040)      SC (f32)  } W3bf (bf16) overlays U+SC in g4
//   ws [74711040, 78643200)      PR (f32)
// ---------------------------------------------------------------------------
extern "C" void kernel_launch(void* const* d_in, const int* in_sizes, int n_in,
                              void* d_out, int out_size, void* d_ws, size_t ws_size,
                              hipStream_t stream) {
  const float* emb1 = (const float*)d_in[0];
  const float* emba = (const float*)d_in[1];
  const float* Wq   = (const float*)d_in[2];
  const float* Wk   = (const float*)d_in[3];
  const float* Wv   = (const float*)d_in[4];
  const float* Wo   = (const float*)d_in[5];
  float* out = (float*)d_out;
  char* ws = (char*)d_ws;

  ushort* embaBF = (ushort*)(ws);
  float*  S      = (float*)(ws + 62914560);
  float*  T      = (float*)(ws + 62914560);
  float*  U      = (float*)(ws + 66846720);
  ushort* W3bf   = (ushort*)(ws + 66846720);
  float*  SCb    = (float*)(ws + 70778880);
  float*  PRb    = (float*)(ws + 74711040);
  float*  P      = out;
  ushort* emb1BF = (ushort*)((char*)d_out + 33554432);
  float*  stats  = (float*)(ws + 66846720);  // U region, dead after g2

  // 1) f32 -> bf16 conversions
  k_cvt<<<16384, 256, 0, stream>>>((const float4*)emb1, (ushort4*)emb1BF, 4194304);
  k_cvt<<<30720, 256, 0, stream>>>((const float4*)emba, (ushort4*)embaBF, 7864320);

  // 2) S partials (MFMA v3, tr_b16 + global_load_lds) + reduce/unswizzle
  k1_mfma<<<dim3(32, NSPLIT), 512, 0, stream>>>(emb1BF, embaBF, P);
  k_reduce_frag<<<dim3(32, 32), 256, 0, stream>>>((const f32x4*)P, S);

  // 3) chain (flat-batched f32 GEMMs + stats + softmax)
  k_g1<<<dim3(4, 2, 40), 256, 0, stream>>>(Wq, S, U);
  k_g2<<<dim3(64, 5), 256, 0, stream>>>(U, Wk, SCb);
  k_stats<<<32, 1024, 0, stream>>>(SCb, stats);
  k_softmax<<<dim3(32, 4), 512, 0, stream>>>(SCb, stats, PRb);
  k_g3<<<dim3(64, 5), 256, 0, stream>>>(PRb, Wv, T);
  k_g4<<<dim3(4, 8, 40), 256, 0, stream>>>(Wo, T, W3bf);

  // 4) O1[b] = embaBF[b] @ W3bf[b]^T  (MFMA, XCD-swizzled)
  k3_mfma<<<1024, 256, 0, stream>>>(embaBF, W3bf, out);
}